// Round 1
// baseline (320.190 us; speedup 1.0000x reference)
//
#include <hip/hip_runtime.h>
#include <math.h>

// NeRF volume rendering: N=65536 rays, S=192 samples.
// One wave (64 lanes) per ray; 3 sequential chunks of 64 samples each.
// Cumprod via in-wave shuffle prefix-product scan + inter-chunk scalar carry.
// Memory-bound: ~405 MB total traffic -> ~64 us floor at 6.3 TB/s.

constexpr int kRays = 65536;
constexpr int kS = 192;

__global__ __launch_bounds__(256) void nerf_render_kernel(
    const float* __restrict__ rgb,      // [N, S, 3]
    const float* __restrict__ sigma,    // [N, S]
    const float* __restrict__ z_vals,   // [N, S]
    const float* __restrict__ rays_d,   // [N, 3]
    float* __restrict__ out)            // concat: rgb_map, depth, acc, weights, disp, trans, alpha
{
    const int lane = threadIdx.x & 63;
    const int ray  = (blockIdx.x << 2) + (threadIdx.x >> 6);  // 4 waves/block

    float* __restrict__ rgb_map   = out;                                        // [N,3]
    float* __restrict__ depth_map = out + (size_t)kRays * 3;                    // [N]
    float* __restrict__ acc_map   = out + (size_t)kRays * 4;                    // [N]
    float* __restrict__ weights_o = out + (size_t)kRays * 5;                    // [N,S]
    float* __restrict__ disp_map  = out + (size_t)kRays * 5 + (size_t)kRays * kS;      // [N]
    float* __restrict__ trans_o   = out + (size_t)kRays * 6 + (size_t)kRays * kS;      // [N,S]
    float* __restrict__ alpha_o   = out + (size_t)kRays * 6 + (size_t)kRays * kS * 2;  // [N,S]

    // ray direction norm (same 3 floats for all lanes -> cached/broadcast)
    const float dx = rays_d[ray * 3 + 0];
    const float dy = rays_d[ray * 3 + 1];
    const float dz = rays_d[ray * 3 + 2];
    const float nrm = sqrtf(dx * dx + dy * dy + dz * dz);

    const size_t base = (size_t)ray * kS;

    float carry = 1.0f;                       // running transmittance across chunks
    float sr = 0.f, sg = 0.f, sb = 0.f;       // rgb_map partials
    float sd = 0.f, sw = 0.f;                 // depth_map / acc_map partials

    #pragma unroll
    for (int c = 0; c < 3; ++c) {
        const int idx = c * 64 + lane;        // sample index, contiguous per wave
        const float zc = z_vals[base + idx];
        float dist;
        if (idx < kS - 1) {
            // z[idx+1] is in the same cache lines the wave just read -> L1 hit
            dist = (z_vals[base + idx + 1] - zc) * nrm;
        } else {
            dist = 1e10f * nrm;               // infinite far segment
        }

        float s = sigma[base + idx];
        s = s > 0.f ? s : 0.f;                // relu
        const float e = expf(-s * dist);
        const float alpha = 1.0f - e;
        const float om = 1.0f - alpha;        // match reference rounding exactly

        // inclusive prefix product of om across the 64-lane wave
        float p = om;
        #pragma unroll
        for (int d = 1; d < 64; d <<= 1) {
            const float v = __shfl_up(p, d, 64);
            if (lane >= d) p *= v;
        }
        // exclusive prefix (no division: safe when om == 0 at alpha == 1)
        float excl = __shfl_up(p, 1, 64);
        if (lane == 0) excl = 1.0f;

        const float trans = carry * excl;     // T_i = prod_{j<i} (1 - alpha_j)
        const float w = alpha * trans;

        trans_o[base + idx]   = trans;
        alpha_o[base + idx]   = alpha;
        weights_o[base + idx] = w;

        const size_t rb = (base + idx) * 3;
        sr += w * rgb[rb + 0];
        sg += w * rgb[rb + 1];
        sb += w * rgb[rb + 2];
        sd += w * zc;
        sw += w;

        carry *= __shfl(p, 63, 64);           // total product of this chunk
    }

    // 64-lane butterfly reduction for the 5 per-ray scalars
    #pragma unroll
    for (int d = 1; d < 64; d <<= 1) {
        sr += __shfl_xor(sr, d, 64);
        sg += __shfl_xor(sg, d, 64);
        sb += __shfl_xor(sb, d, 64);
        sd += __shfl_xor(sd, d, 64);
        sw += __shfl_xor(sw, d, 64);
    }

    if (lane == 0) {
        rgb_map[ray * 3 + 0] = sr;
        rgb_map[ray * 3 + 1] = sg;
        rgb_map[ray * 3 + 2] = sb;
        depth_map[ray] = sd;
        acc_map[ray]   = sw;
        const float q = fmaxf(1e-10f, sd / sw);
        disp_map[ray] = 1.0f / q;
    }
}

extern "C" void kernel_launch(void* const* d_in, const int* in_sizes, int n_in,
                              void* d_out, int out_size, void* d_ws, size_t ws_size,
                              hipStream_t stream) {
    const float* rgb    = (const float*)d_in[0];
    const float* sigma  = (const float*)d_in[1];
    const float* z_vals = (const float*)d_in[2];
    const float* rays_d = (const float*)d_in[3];
    float* out = (float*)d_out;

    // 4 rays per 256-thread block (one wave per ray)
    const int blocks = kRays / 4;  // 16384
    nerf_render_kernel<<<blocks, 256, 0, stream>>>(rgb, sigma, z_vals, rays_d, out);
}